// Round 4
// baseline (99.771 us; speedup 1.0000x reference)
//
#include <hip/hip_runtime.h>

// B=8, L=4096, D=1024, window W=128. out[b,l,d] = sort128( v[b,(l-d)%L,d] )
constexpr int kL   = 4096;
constexpr int kD   = 1024;
constexpr int kW   = 128;
constexpr int kDT  = 32;   // columns per block
constexpr int kNWB = 2;    // windows per block
// full band span = kNWB*kW + kDT - 1 = 287 rows; staged in TWO phases through
// one 160-row buffer so LDS = 160*32*4 = 20 KB -> 8 blocks/CU (was 36.9 KB -> 4).
constexpr int kCUT = 160;

// Bitonic network with K, J as TEMPLATE constants: after the i-loop unrolls,
// every val[] index is parse-time constant -> SROA keeps the array in regs.
template<int K, int J>
__device__ __forceinline__ void bitonic_stage(float (&val)[kW]) {
    #pragma unroll
    for (int i = 0; i < kW; ++i) {
        const int ij = i ^ J;
        if (ij > i) {
            const bool up = ((i & K) == 0);
            const float a = val[i], c = val[ij];
            const float lo = fminf(a, c), hi = fmaxf(a, c);
            val[i]  = up ? lo : hi;
            val[ij] = up ? hi : lo;
        }
    }
    if constexpr (J > 1)       bitonic_stage<K, J / 2>(val);
    else if constexpr (K < kW) bitonic_stage<K * 2, K>(val);
}

__global__ __launch_bounds__(64, 1) void SWD20_sortwin_kernel(
    const float* __restrict__ v, float* __restrict__ out) {
    __shared__ float band[kCUT * kDT];   // 20 KB, reused by both phases

    const int tid = threadIdx.x;
    const int d0  = blockIdx.x * kDT;
    const int w0  = blockIdx.y * kNWB;
    const int b   = blockIdx.z;

    const size_t base = (size_t)b * kL * kD;
    const int r_lo = w0 * kW - d0 - (kDT - 1);  // lowest absolute row needed

    const int wl = tid >> 5;                // window within block (0..1)
    const int dl = tid & 31;                // column within tile
    const int sbase = wl * kW + (kDT - 1) - dl;  // window start in band coords

    float val[kW];

    // ---- phase A: stage band rows [0, 160), coalesced float4 ----
    #pragma unroll
    for (int it = 0; it < (kCUT * kDT / 4) / 64; ++it) {   // 20 iters
        const int c  = it * 64 + tid;
        const int s  = c >> 3;              // band row (8 float4 per row)
        const int fo = (c & 7) << 2;
        const int gr = (r_lo + s + 2 * kL) & (kL - 1);
        *reinterpret_cast<float4*>(&band[c * 4]) =
            *reinterpret_cast<const float4*>(v + base + (size_t)gr * kD + d0 + fo);
    }
    __syncthreads();
    // extract window elements that live in rows [0, kCUT)
    #pragma unroll
    for (int i = 0; i < kW; ++i) {
        const int s = sbase + i;
        if (s < kCUT) val[i] = band[s * kDT + dl];
    }
    __syncthreads();   // all phase-A reads done before overwrite

    // ---- phase B: stage band rows [160, 288) into the same buffer ----
    #pragma unroll
    for (int it = 0; it < ((288 - kCUT) * kDT / 4) / 64; ++it) {  // 16 iters
        const int c  = it * 64 + tid;
        const int s  = c >> 3;
        const int fo = (c & 7) << 2;
        const int gr = (r_lo + kCUT + s + 2 * kL) & (kL - 1);
        *reinterpret_cast<float4*>(&band[c * 4]) =
            *reinterpret_cast<const float4*>(v + base + (size_t)gr * kD + d0 + fo);
    }
    __syncthreads();
    #pragma unroll
    for (int i = 0; i < kW; ++i) {
        const int s = sbase + i;
        if (s >= kCUT) val[i] = band[(s - kCUT) * kDT + dl];
    }

    // ---- bitonic sort, 128 elements ascending, fully in registers ----
    bitonic_stage<2, 1>(val);

    // ---- store: at fixed i, lanes write 2 contiguous 128B segments.
    // Non-temporal: output is never re-read; keep v resident in L3.
    float* op = out + base + ((size_t)(w0 + wl) * kW) * kD + d0 + dl;
    #pragma unroll
    for (int i = 0; i < kW; ++i)
        __builtin_nontemporal_store(val[i], op + (size_t)i * kD);
}

extern "C" void kernel_launch(void* const* d_in, const int* in_sizes, int n_in,
                              void* d_out, int out_size, void* d_ws, size_t ws_size,
                              hipStream_t stream) {
    const float* v = (const float*)d_in[2];   // inputs: q, k, v — only v used
    float* out = (float*)d_out;
    const int B = in_sizes[2] / (kL * kD);    // = 8
    dim3 grid(kD / kDT, (kL / kW) / kNWB, B); // 32 x 16 x 8 = 4096 blocks
    dim3 block(64);
    hipLaunchKernelGGL(SWD20_sortwin_kernel, grid, block, 0, stream, v, out);
}

// Round 5
// 53.753 us; speedup vs baseline: 1.8561x; 1.8561x over previous
//
#include <hip/hip_runtime.h>

// B=8, L=4096, D=1024, W=128. out[b,l,d] = sort128_window( v[b,(l-d)%L,d] )
constexpr int kL   = 4096;
constexpr int kD   = 1024;
constexpr int kW   = 128;
constexpr int kDT  = 32;   // columns per block
constexpr int kNWB = 2;    // windows per block
constexpr int kROWS = kNWB * kW + kDT;  // 287 -> 288
// band = 288*32*4 = 36,864 B; block = 128 threads (2 waves); 4 blocks/CU.

// Bitonic sort, all indices parse-time constants (SROA -> registers).
template<int K, int J, int N>
__device__ __forceinline__ void bitonic_stage(float (&e)[N]) {
    #pragma unroll
    for (int i = 0; i < N; ++i) {
        const int ij = i ^ J;
        if (ij > i) {
            const bool up = ((i & K) == 0);
            const float a = e[i], c = e[ij];
            const float lo = fminf(a, c), hi = fmaxf(a, c);
            e[i]  = up ? lo : hi;
            e[ij] = up ? hi : lo;
        }
    }
    if constexpr (J > 1)    bitonic_stage<K, J / 2, N>(e);
    else if constexpr (K < N) bitonic_stage<K * 2, K, N>(e);
}

// Ascending merge of a bitonic sequence of length N (stages J..1).
template<int J, int N>
__device__ __forceinline__ void bitonic_merge(float (&e)[N]) {
    #pragma unroll
    for (int i = 0; i < N; ++i) {
        const int ij = i ^ J;
        if (ij > i) {
            const float a = e[i], c = e[ij];
            e[i]  = fminf(a, c);
            e[ij] = fmaxf(a, c);
        }
    }
    if constexpr (J > 1) bitonic_merge<J / 2, N>(e);
}

__global__ __launch_bounds__(128, 2) void SWD20_sortwin_kernel(
    const float* __restrict__ v, float* __restrict__ out) {
    __shared__ float band[kROWS * kDT];

    const int tid  = threadIdx.x;
    const int d0   = blockIdx.x * kDT;
    const int w0   = blockIdx.y * kNWB;
    const int b    = blockIdx.z;

    const size_t base = (size_t)b * kL * kD;
    const int r_lo = w0 * kW - d0 - (kDT - 1);   // lowest absolute row needed

    // ---- stage band: 288 rows x 32 cols, coalesced float4 (18 iters) ----
    #pragma unroll
    for (int it = 0; it < (kROWS * kDT / 4) / 128; ++it) {
        const int c  = it * 128 + tid;      // float4 index
        const int s  = c >> 3;              // band row (8 float4/row)
        const int fo = (c & 7) << 2;
        const int gr = (r_lo + s + 2 * kL) & (kL - 1);
        *reinterpret_cast<float4*>(&band[c * 4]) =
            *reinterpret_cast<const float4*>(v + base + (size_t)gr * kD + d0 + fo);
    }
    __syncthreads();

    // ---- each PAIR of lanes (l, l+32) owns one (window, column) sort ----
    const int wl   = tid >> 6;              // window = wave id (0..1)
    const int lane = tid & 63;
    const int half = lane >> 5;             // 0: elems 0..63, 1: elems 64..127
    const int dl   = lane & 31;             // column within tile
    const int sbase = wl * kW + (kDT - 1) - dl + half * 64;
    // sign trick: hi half sorts NEGATED values ascending (= real descending),
    // so the cross-lane bitonic stage is one uniform fminf for both halves.
    const float sgn = half ? -1.0f : 1.0f;

    float e[64];
    #pragma unroll
    for (int j = 0; j < 64; ++j)
        e[j] = band[(sbase + j) * kDT + dl] * sgn;

    // sort own 64 ascending (hi lane: real values descending)
    bitonic_stage<2, 1, 64>(e);

    // cross-lane merge stage (j=64 of the 128 network):
    // lo: A[i]=min(A[i], realHi[i]);  hi: t[i]=min(t[i],-A[i]) = -max(real)
    #pragma unroll
    for (int j = 0; j < 64; ++j) {
        const float r = __shfl_xor(e[j], 32);
        e[j] = fminf(e[j], -r);
    }
    // restore real values on hi half; both halves now bitonic, lo<=hi
    #pragma unroll
    for (int j = 0; j < 64; ++j) e[j] *= sgn;

    // lane-local ascending merge of the bitonic 64
    bitonic_merge<32, 64>(e);

    // ---- store: fixed j => lanes write two contiguous 128B segments.
    // Non-temporal: output never re-read; keeps v resident in L3 (R4: fetch~0).
    float* op = out + base + ((size_t)(w0 + wl) * kW + half * 64) * kD + d0 + dl;
    #pragma unroll
    for (int j = 0; j < 64; ++j)
        __builtin_nontemporal_store(e[j], op + (size_t)j * kD);
}

extern "C" void kernel_launch(void* const* d_in, const int* in_sizes, int n_in,
                              void* d_out, int out_size, void* d_ws, size_t ws_size,
                              hipStream_t stream) {
    const float* v = (const float*)d_in[2];   // inputs: q, k, v — only v used
    float* out = (float*)d_out;
    const int B = in_sizes[2] / (kL * kD);    // = 8
    dim3 grid(kD / kDT, (kL / kW) / kNWB, B); // 32 x 16 x 8 = 4096 blocks
    dim3 block(128);
    hipLaunchKernelGGL(SWD20_sortwin_kernel, grid, block, 0, stream, v, out);
}